// Round 10
// baseline (134.991 us; speedup 1.0000x reference)
//
#include <hip/hip_runtime.h>
#include <stdint.h>

#define B_ 2
#define T_ 2048
#define C_ 1024
#define H_ 16
#define D_ 64
#define M_ (B_*T_)
#define BHTD_ (B_*H_*T_*D_)

typedef __bf16 bf16x8 __attribute__((ext_vector_type(8)));
typedef __bf16 bf16x4 __attribute__((ext_vector_type(4)));
typedef __bf16 bf16x2 __attribute__((ext_vector_type(2)));
typedef float f32x4 __attribute__((ext_vector_type(4)));
typedef float f32x16 __attribute__((ext_vector_type(16)));

static __device__ __forceinline__ unsigned short f32_bf16(float f) {
    unsigned int u = __float_as_uint(f);
    u += 0x7FFFu + ((u >> 16) & 1u);   // round-to-nearest-even
    return (unsigned short)(u >> 16);
}

static __device__ __forceinline__ int pack_bf16_2(float a, float b) {
    bf16x2 v = {(__bf16)a, (__bf16)b};
    return __builtin_bit_cast(int, v);
}

// ---------------- cast f32 -> bf16 (vectorized) ----------------
__global__ void cast_kernel(const float* __restrict__ in, unsigned short* __restrict__ out, int n) {
    int i = (blockIdx.x * 256 + threadIdx.x) * 4;
    if (i >= n) return;
    float4 f = *(const float4*)(in + i);
    ushort4 o;
    o.x = f32_bf16(f.x); o.y = f32_bf16(f.y); o.z = f32_bf16(f.z); o.w = f32_bf16(f.w);
    *(ushort4*)(out + i) = o;
}

// ---------------- transpose+cast: W [K][N] f32 -> Wt [N][K] bf16 ----------------
__global__ void transpose_cast_kernel(const float* __restrict__ W, unsigned short* __restrict__ Wt,
                                      int K, int N) {
    __shared__ float tile[32][33];
    int n0 = blockIdx.x * 32, k0 = blockIdx.y * 32;
    int tx = threadIdx.x, ty = threadIdx.y;
    #pragma unroll
    for (int j = 0; j < 32; j += 8)
        tile[ty + j][tx] = W[(size_t)(k0 + ty + j) * N + n0 + tx];
    __syncthreads();
    #pragma unroll
    for (int j = 0; j < 32; j += 8)
        Wt[(size_t)(n0 + ty + j) * K + k0 + tx] = f32_bf16(tile[tx][ty + j]);
}

// ---------------- GEMM (unchanged: 2-phase dbuf gll staging) ----------------
template<int EPI>
__global__ __launch_bounds__(256) void gemm_bt(
    const unsigned short* __restrict__ A,
    const unsigned short* __restrict__ Bt,
    const float* __restrict__ bias,
    unsigned short* __restrict__ out_bf16,
    float* __restrict__ out_f32,
    int M, int N, int K)
{
    __shared__ unsigned short As[2][128 * 32];
    __shared__ unsigned short Bs[2][128 * 32];
    int tid = threadIdx.x;
    int lane = tid & 63, wid = tid >> 6;
    int fr = lane & 15, fg = lane >> 4;
    int row0 = blockIdx.x * 128, col0 = blockIdx.y * 128;
    int wm = (wid >> 1) * 64, wn = (wid & 1) * 64;

    f32x4 acc[4][4];
    #pragma unroll
    for (int i = 0; i < 4; ++i)
        #pragma unroll
        for (int j = 0; j < 4; ++j)
            acc[i][j] = (f32x4){0.f, 0.f, 0.f, 0.f};

    const int srw = lane >> 2;
    const int scl = (lane & 3) * 8;
    const int c0 = wid * 2, c1 = wid * 2 + 1;

    auto stage = [&](int buf, int k0) {
        __builtin_amdgcn_global_load_lds(
            (const __attribute__((address_space(1))) void*)(A + (size_t)(row0 + c0 * 16 + srw) * K + k0 + scl),
            (__attribute__((address_space(3))) void*)(As[buf] + c0 * 512), 16, 0, 0);
        __builtin_amdgcn_global_load_lds(
            (const __attribute__((address_space(1))) void*)(A + (size_t)(row0 + c1 * 16 + srw) * K + k0 + scl),
            (__attribute__((address_space(3))) void*)(As[buf] + c1 * 512), 16, 0, 0);
        __builtin_amdgcn_global_load_lds(
            (const __attribute__((address_space(1))) void*)(Bt + (size_t)(col0 + c0 * 16 + srw) * K + k0 + scl),
            (__attribute__((address_space(3))) void*)(Bs[buf] + c0 * 512), 16, 0, 0);
        __builtin_amdgcn_global_load_lds(
            (const __attribute__((address_space(1))) void*)(Bt + (size_t)(col0 + c1 * 16 + srw) * K + k0 + scl),
            (__attribute__((address_space(3))) void*)(Bs[buf] + c1 * 512), 16, 0, 0);
    };

    stage(0, 0);
    __syncthreads();

    int cur = 0;
    for (int k0 = 0; k0 < K; k0 += 32) {
        if (k0 + 32 < K) stage(cur ^ 1, k0 + 32);

        bf16x8 af[4], bfr[4];
        #pragma unroll
        for (int i = 0; i < 4; ++i) {
            af[i]  = *(const bf16x8*)(As[cur] + (wm + i * 16 + fr) * 32 + fg * 8);
            bfr[i] = *(const bf16x8*)(Bs[cur] + (wn + i * 16 + fr) * 32 + fg * 8);
        }
        #pragma unroll
        for (int mi = 0; mi < 4; ++mi)
            #pragma unroll
            for (int ni = 0; ni < 4; ++ni)
                acc[mi][ni] = __builtin_amdgcn_mfma_f32_16x16x32_bf16(af[mi], bfr[ni], acc[mi][ni], 0, 0, 0);

        __syncthreads();
        cur ^= 1;
    }

    #pragma unroll
    for (int mi = 0; mi < 4; ++mi) {
        int rowb = row0 + wm + mi * 16 + fg * 4;
        #pragma unroll
        for (int ni = 0; ni < 4; ++ni) {
            int col = col0 + wn + ni * 16 + fr;
            float bv = bias[col];
            #pragma unroll
            for (int r = 0; r < 4; ++r) {
                float v = acc[mi][ni][r] + bv;
                int rr = rowb + r;
                if (EPI == 0) {
                    int part = col >> 10, c = col & 1023;
                    int h = c >> 6, d = c & 63;
                    int b = rr >> 11, t = rr & 2047;
                    if (part == 0) v *= 0.18033688011112042f;   // fold log2(e)/sqrt(D) into Q
                    size_t idx;
                    if (part == 2)
                        idx = (size_t)2 * BHTD_ + ((size_t)(b * H_ + h) * D_ + d) * T_ + t;
                    else
                        idx = (size_t)part * BHTD_ + ((size_t)(b * H_ + h) * T_ + t) * D_ + d;
                    out_bf16[idx] = f32_bf16(v);
                } else {
                    out_f32[(size_t)rr * N + col] = v;
                }
            }
        }
    }
}

// ---------------- causal flash attention v10: wave-split dual-chunk ----------------
// 512 blocks x 256 threads (4 waves). Waves 0,1 own hi chunk (31-p), waves 2,3
// own lo chunk (p); each wave = 32 q rows via 32x32 MFMA, in-register P
// (pack+permlane32_swap, verified in v9). Block = 66 active wave-tiles; co-CU
// block pair (iq, iq+8) has nthi sum = 49 (p(iq)=iq<8?iq:23-iq) -> balanced
// makespan AND 8 resident waves/CU. Lo waves idle-at-barrier after their span
// but keep staging. K/V^T via global_load_lds (inverse-swizzled source), dbuf.
__global__ __launch_bounds__(256) void attn_kernel(
    const unsigned short* __restrict__ qg,
    const unsigned short* __restrict__ kg,
    const unsigned short* __restrict__ vtg,  // [bh][D][T]
    unsigned short* __restrict__ y)
{
    const int id = blockIdx.x;
    const int xcd = id & 7, loc = id >> 3;      // loc in [0,64)
    const int bh = xcd * 4 + (loc & 3);         // 4 heads per XCD -> K/V L2-resident
    const int iq = loc >> 2;                    // [0,16)
    const int p = (iq < 8) ? iq : 23 - iq;      // complementary pairing: p(iq)+p(iq+8)=15
    const int chhi = 31 - p, chlo = p;
    const int b = bh >> 4, h = bh & 15;
    const int tid = threadIdx.x, wid = tid >> 6, lane = tid & 63;
    const int lq = lane & 31, hi = lane >> 5;

    const unsigned short* qp = qg + (size_t)bh * (T_ * D_);
    const char* kpB = (const char*)(kg + (size_t)bh * (T_ * D_));
    const char* vpB = (const char*)(vtg + (size_t)bh * (D_ * T_));

    __shared__ __align__(16) char Ks[2][8192];   // [kv][d] bf16, 128B rows, XOR-swizzled
    __shared__ __align__(16) char Vs[2][8192];   // [d][kv] bf16, 128B rows, XOR-swizzled

    const int mych = (wid < 2) ? chhi : chlo;    // wave's chunk
    const int r0 = mych * 64 + (wid & 1) * 32;   // wave's 32 q rows
    const int nthi = chhi + 1;                   // block loop length
    const int ntlo = chlo + 1;                   // lo-wave active span
    const bool is_hi = (wid < 2);

    // Q fragments (pre-scaled by log2e/sqrt(D)): B-operand of mfma(K,Q)
    bf16x8 qf[4];
    #pragma unroll
    for (int ds = 0; ds < 4; ++ds)
        qf[ds] = *(const bf16x8*)(qp + (size_t)(r0 + lq) * D_ + ds * 16 + hi * 8);

    f32x16 oT0, oT1;
    #pragma unroll
    for (int e = 0; e < 16; ++e) { oT0[e] = 0.f; oT1[e] = 0.f; }
    float lrun = 0.f;

    // staging: 4 waves x (2 K + 2 V) gll chunks of 8 rows / 1KB each
    const int srow8 = lane >> 3;           // row within 8-row chunk
    const int scol  = (lane & 7) * 16;     // byte col within 128B row
    const int ssw   = srow8 << 4;          // inverse swizzle on source

    auto stage = [&](int buf, int kv0) {
        #pragma unroll
        for (int bc = 0; bc < 2; ++bc) {
            const int rbase = wid * 16 + bc * 8;
            __builtin_amdgcn_global_load_lds(
                (const __attribute__((address_space(1))) void*)
                    (kpB + (size_t)(kv0 + rbase + srow8) * 128 + (scol ^ ssw)),
                (__attribute__((address_space(3))) void*)(Ks[buf] + rbase * 128), 16, 0, 0);
            __builtin_amdgcn_global_load_lds(
                (const __attribute__((address_space(1))) void*)
                    (vpB + (size_t)(rbase + srow8) * 4096 + kv0 * 2 + (scol ^ ssw)),
                (__attribute__((address_space(3))) void*)(Vs[buf] + rbase * 128), 16, 0, 0);
        }
    };

    // P -> PV B-frag: 4 packs + 2 permlane32_swap per 16-kv step (verified v9)
    auto make_pb = [&](const f32x16& p4, int g4a) -> bf16x8 {
        int A0 = pack_bf16_2(p4[g4a * 4 + 0], p4[g4a * 4 + 1]);
        int A1 = pack_bf16_2(p4[g4a * 4 + 2], p4[g4a * 4 + 3]);
        int B0 = pack_bf16_2(p4[g4a * 4 + 4], p4[g4a * 4 + 5]);
        int B1 = pack_bf16_2(p4[g4a * 4 + 6], p4[g4a * 4 + 7]);
        auto ra = __builtin_amdgcn_permlane32_swap(A0, B0, false, false);
        auto rb = __builtin_amdgcn_permlane32_swap(A1, B1, false, false);
        int4 w;
        w.x = ra[0]; w.y = rb[0]; w.z = ra[1]; w.w = rb[1];
        return __builtin_bit_cast(bf16x8, w);
    };

    stage(0, 0);
    __syncthreads();

    const int lsw = (lq & 7) << 4;   // read-side swizzle
    int cur = 0;
    for (int t = 0; t < nthi; ++t) {
        const int kv0 = t * 64;
        if (t + 1 < nthi) stage(cur ^ 1, kv0 + 64);   // prefetch under compute

        const bool active = is_hi || (t < ntlo);       // wave-uniform
        if (active) {
            const char* Kb = Ks[cur];
            const char* Vb = Vs[cur];
            const bool diag = (t == mych);
            const bool do_n1 = !(diag && (wid & 1) == 0);  // lower sub-rows: upper 32 kv all masked

            // ---- S^T = mfma(K, Q) ----
            f32x16 s0, s1;
            #pragma unroll
            for (int e = 0; e < 16; ++e) { s0[e] = 0.f; s1[e] = 0.f; }
            #pragma unroll
            for (int ds = 0; ds < 4; ++ds) {
                bf16x8 kf = *(const bf16x8*)(Kb + lq * 128 + ((ds * 32 + hi * 16) ^ lsw));
                s0 = __builtin_amdgcn_mfma_f32_32x32x16_bf16(kf, qf[ds], s0, 0, 0, 0);
            }
            if (do_n1) {
                #pragma unroll
                for (int ds = 0; ds < 4; ++ds) {
                    bf16x8 kf = *(const bf16x8*)(Kb + (32 + lq) * 128 + ((ds * 32 + hi * 16) ^ lsw));
                    s1 = __builtin_amdgcn_mfma_f32_32x32x16_bf16(kf, qf[ds], s1, 0, 0, 0);
                }
            }

            // ---- V^T A-frags (issue early) ----
            bf16x8 vf[2][4];
            #pragma unroll
            for (int dd = 0; dd < 2; ++dd)
                #pragma unroll
                for (int st = 0; st < 2; ++st)
                    vf[dd][st] = *(const bf16x8*)(Vb + (dd * 32 + lq) * 128 +
                                                  ((st * 32 + hi * 16) ^ lsw));
            if (do_n1) {
                #pragma unroll
                for (int dd = 0; dd < 2; ++dd)
                    #pragma unroll
                    for (int st = 2; st < 4; ++st)
                        vf[dd][st] = *(const bf16x8*)(Vb + (dd * 32 + lq) * 128 +
                                                      ((st * 32 + hi * 16) ^ lsw));
            }

            // ---- no-max softmax (C layout: kv_local = (e&3) + 8*(e>>2) + 4*hi) ----
            const int qrow = r0 + lq;
            if (diag && (wid & 1) == 0) {
                #pragma unroll
                for (int e = 0; e < 16; ++e) {
                    const int kvl = (e & 3) + ((e >> 2) << 3) + hi * 4;
                    s0[e] = exp2f((kv0 + kvl <= qrow) ? s0[e] : -1e30f);
                }
            } else if (diag) {
                #pragma unroll
                for (int e = 0; e < 16; ++e) {
                    const int kvl = (e & 3) + ((e >> 2) << 3) + hi * 4;
                    s0[e] = exp2f((kv0 + kvl <= qrow) ? s0[e] : -1e30f);
                }
            } else {
                #pragma unroll
                for (int e = 0; e < 16; ++e) s0[e] = exp2f(s0[e]);
            }
            {
                float a0 = (s0[0] + s0[1]) + (s0[2] + s0[3]);
                float a1 = (s0[4] + s0[5]) + (s0[6] + s0[7]);
                float a2 = (s0[8] + s0[9]) + (s0[10] + s0[11]);
                float a3 = (s0[12] + s0[13]) + (s0[14] + s0[15]);
                lrun += (a0 + a1) + (a2 + a3);
            }
            if (do_n1) {
                if (diag) {
                    #pragma unroll
                    for (int e = 0; e < 16; ++e) {
                        const int kvl = 32 + (e & 3) + ((e >> 2) << 3) + hi * 4;
                        s1[e] = exp2f((kv0 + kvl <= qrow) ? s1[e] : -1e30f);
                    }
                } else {
                    #pragma unroll
                    for (int e = 0; e < 16; ++e) s1[e] = exp2f(s1[e]);
                }
                float a0 = (s1[0] + s1[1]) + (s1[2] + s1[3]);
                float a1 = (s1[4] + s1[5]) + (s1[6] + s1[7]);
                float a2 = (s1[8] + s1[9]) + (s1[10] + s1[11]);
                float a3 = (s1[12] + s1[13]) + (s1[14] + s1[15]);
                lrun += (a0 + a1) + (a2 + a3);
            }

            // ---- O^T += V^T P^T (in-register P) ----
            {
                bf16x8 pb = make_pb(s0, 0);
                oT0 = __builtin_amdgcn_mfma_f32_32x32x16_bf16(vf[0][0], pb, oT0, 0, 0, 0);
                oT1 = __builtin_amdgcn_mfma_f32_32x32x16_bf16(vf[1][0], pb, oT1, 0, 0, 0);
                pb = make_pb(s0, 2);
                oT0 = __builtin_amdgcn_mfma_f32_32x32x16_bf16(vf[0][1], pb, oT0, 0, 0, 0);
                oT1 = __builtin_amdgcn_mfma_f32_32x32x16_bf16(vf[1][1], pb, oT1, 0, 0, 0);
            }
            if (do_n1) {
                bf16x8 pb = make_pb(s1, 0);
                oT0 = __builtin_amdgcn_mfma_f32_32x32x16_bf16(vf[0][2], pb, oT0, 0, 0, 0);
                oT1 = __builtin_amdgcn_mfma_f32_32x32x16_bf16(vf[1][2], pb, oT1, 0, 0, 0);
                pb = make_pb(s1, 2);
                oT0 = __builtin_amdgcn_mfma_f32_32x32x16_bf16(vf[0][3], pb, oT0, 0, 0, 0);
                oT1 = __builtin_amdgcn_mfma_f32_32x32x16_bf16(vf[1][3], pb, oT1, 0, 0, 0);
            }
        }

        __syncthreads();   // drains prefetch gll; all waves done with cur buffer
        cur ^= 1;
    }

    // ---- epilogue: l reduce across hi halves, normalize, packed stores ----
    const float ls = lrun + __shfl_xor(lrun, 32);
    const float inv = 1.f / ls;
    const int trow = r0 + lq;
    unsigned short* yrow = y + ((size_t)b * T_ + trow) * C_ + h * 64;
    #pragma unroll
    for (int dd = 0; dd < 2; ++dd) {
        const f32x16& o = dd ? oT1 : oT0;
        #pragma unroll
        for (int g4 = 0; g4 < 4; ++g4) {
            bf16x4 ov = {(__bf16)(o[g4 * 4 + 0] * inv), (__bf16)(o[g4 * 4 + 1] * inv),
                         (__bf16)(o[g4 * 4 + 2] * inv), (__bf16)(o[g4 * 4 + 3] * inv)};
            *(uint2*)(yrow + dd * 32 + g4 * 8 + hi * 4) = __builtin_bit_cast(uint2, ov);
        }
    }
}

// ---------------- launch ----------------
extern "C" void kernel_launch(void* const* d_in, const int* in_sizes, int n_in,
                              void* d_out, int out_size, void* d_ws, size_t ws_size,
                              hipStream_t stream) {
    const float* x     = (const float*)d_in[0];
    const float* Wqkv  = (const float*)d_in[1];
    const float* bqkv  = (const float*)d_in[2];
    const float* Wproj = (const float*)d_in[3];
    const float* bproj = (const float*)d_in[4];
    float* out = (float*)d_out;

    char* ws = (char*)d_ws;
    unsigned short* x_bf    = (unsigned short*)(ws);                 //  8 MB
    unsigned short* wqkv_t  = (unsigned short*)(ws + 8388608);       //  6 MB
    unsigned short* wproj_t = (unsigned short*)(ws + 14680064);      //  2 MB
    unsigned short* qkv     = (unsigned short*)(ws + 16777216);      // 24 MB
    unsigned short* ybuf    = (unsigned short*)(ws + 41943040);      //  8 MB

    cast_kernel<<<(M_ * C_) / 4 / 256, 256, 0, stream>>>(x, x_bf, M_ * C_);
    transpose_cast_kernel<<<dim3(3072 / 32, 1024 / 32), dim3(32, 8), 0, stream>>>(Wqkv, wqkv_t, 1024, 3072);
    transpose_cast_kernel<<<dim3(1024 / 32, 1024 / 32), dim3(32, 8), 0, stream>>>(Wproj, wproj_t, 1024, 1024);

    gemm_bt<0><<<dim3(M_ / 128, 3072 / 128), 256, 0, stream>>>(
        x_bf, wqkv_t, bqkv, qkv, nullptr, M_, 3072, 1024);

    attn_kernel<<<dim3(512), 256, 0, stream>>>(
        qkv, qkv + (size_t)BHTD_, qkv + 2 * (size_t)BHTD_, ybuf);

    gemm_bt<1><<<dim3(M_ / 128, 1024 / 128), 256, 0, stream>>>(
        ybuf, wproj_t, bproj, nullptr, out, M_, 1024, 1024);
}

// Round 11
// 127.792 us; speedup vs baseline: 1.0563x; 1.0563x over previous
//
#include <hip/hip_runtime.h>
#include <stdint.h>

#define B_ 2
#define T_ 2048
#define C_ 1024
#define H_ 16
#define D_ 64
#define M_ (B_*T_)
#define BHTD_ (B_*H_*T_*D_)

typedef __bf16 bf16x8 __attribute__((ext_vector_type(8)));
typedef __bf16 bf16x4 __attribute__((ext_vector_type(4)));
typedef float f32x4 __attribute__((ext_vector_type(4)));

static __device__ __forceinline__ unsigned short f32_bf16(float f) {
    unsigned int u = __float_as_uint(f);
    u += 0x7FFFu + ((u >> 16) & 1u);   // round-to-nearest-even
    return (unsigned short)(u >> 16);
}

// ---------------- cast f32 -> bf16 (vectorized) ----------------
__global__ void cast_kernel(const float* __restrict__ in, unsigned short* __restrict__ out, int n) {
    int i = (blockIdx.x * 256 + threadIdx.x) * 4;
    if (i >= n) return;
    float4 f = *(const float4*)(in + i);
    ushort4 o;
    o.x = f32_bf16(f.x); o.y = f32_bf16(f.y); o.z = f32_bf16(f.z); o.w = f32_bf16(f.w);
    *(ushort4*)(out + i) = o;
}

// ---------------- transpose+cast: W [K][N] f32 -> Wt [N][K] bf16 ----------------
__global__ void transpose_cast_kernel(const float* __restrict__ W, unsigned short* __restrict__ Wt,
                                      int K, int N) {
    __shared__ float tile[32][33];
    int n0 = blockIdx.x * 32, k0 = blockIdx.y * 32;
    int tx = threadIdx.x, ty = threadIdx.y;
    #pragma unroll
    for (int j = 0; j < 32; j += 8)
        tile[ty + j][tx] = W[(size_t)(k0 + ty + j) * N + n0 + tx];
    __syncthreads();
    #pragma unroll
    for (int j = 0; j < 32; j += 8)
        Wt[(size_t)(n0 + ty + j) * K + k0 + tx] = f32_bf16(tile[tx][ty + j]);
}

// ---------------- GEMM: triple-buffered, counted-vmcnt, raw s_barrier ----------------
// Stage tile t+2 while computing t. Per wave 4 gll/tile; 2 tiles in flight = 8
// outstanding; "s_waitcnt vmcnt(4); s_barrier" at iteration end waits only the
// OLDEST tile (t+1) -> never drains to 0 in the main loop (T4). Race-free: gll
// for t+2 (into buf (t-1)%3) is issued only after the barrier that guarantees
// all waves consumed tile t-1 (MFMA issue implies ds_read data arrived).
template<int EPI>
__global__ __launch_bounds__(256) void gemm_bt(
    const unsigned short* __restrict__ A,
    const unsigned short* __restrict__ Bt,
    const float* __restrict__ bias,
    unsigned short* __restrict__ out_bf16,
    float* __restrict__ out_f32,
    int M, int N, int K)
{
    __shared__ unsigned short As[3][128 * 32];   // 3 x 8KB
    __shared__ unsigned short Bs[3][128 * 32];
    int tid = threadIdx.x;
    int lane = tid & 63, wid = tid >> 6;
    int fr = lane & 15, fg = lane >> 4;
    int row0 = blockIdx.x * 128, col0 = blockIdx.y * 128;
    int wm = (wid >> 1) * 64, wn = (wid & 1) * 64;

    f32x4 acc[4][4];
    #pragma unroll
    for (int i = 0; i < 4; ++i)
        #pragma unroll
        for (int j = 0; j < 4; ++j)
            acc[i][j] = (f32x4){0.f, 0.f, 0.f, 0.f};

    const int srw = lane >> 2;
    const int scl = (lane & 3) * 8;
    const int c0 = wid * 2, c1 = wid * 2 + 1;

    auto stage = [&](int buf, int k0) {
        __builtin_amdgcn_global_load_lds(
            (const __attribute__((address_space(1))) void*)(A + (size_t)(row0 + c0 * 16 + srw) * K + k0 + scl),
            (__attribute__((address_space(3))) void*)(As[buf] + c0 * 512), 16, 0, 0);
        __builtin_amdgcn_global_load_lds(
            (const __attribute__((address_space(1))) void*)(A + (size_t)(row0 + c1 * 16 + srw) * K + k0 + scl),
            (__attribute__((address_space(3))) void*)(As[buf] + c1 * 512), 16, 0, 0);
        __builtin_amdgcn_global_load_lds(
            (const __attribute__((address_space(1))) void*)(Bt + (size_t)(col0 + c0 * 16 + srw) * K + k0 + scl),
            (__attribute__((address_space(3))) void*)(Bs[buf] + c0 * 512), 16, 0, 0);
        __builtin_amdgcn_global_load_lds(
            (const __attribute__((address_space(1))) void*)(Bt + (size_t)(col0 + c1 * 16 + srw) * K + k0 + scl),
            (__attribute__((address_space(3))) void*)(Bs[buf] + c1 * 512), 16, 0, 0);
    };

    const int nt = K / 32;
    stage(0, 0);
    stage(1, 32);
    asm volatile("s_waitcnt vmcnt(4)\n\ts_barrier" ::: "memory");   // tile 0 resident

    int cur = 0;
    for (int t = 0; t < nt; ++t) {
        const int k0 = t * 32;
        int nxt = cur + 2; if (nxt >= 3) nxt -= 3;
        if (t + 2 < nt) stage(nxt, k0 + 64);    // issue early; lands under compute

        bf16x8 af[4], bfr[4];
        #pragma unroll
        for (int i = 0; i < 4; ++i) {
            af[i]  = *(const bf16x8*)(As[cur] + (wm + i * 16 + fr) * 32 + fg * 8);
            bfr[i] = *(const bf16x8*)(Bs[cur] + (wn + i * 16 + fr) * 32 + fg * 8);
        }
        __builtin_amdgcn_s_setprio(1);
        #pragma unroll
        for (int mi = 0; mi < 4; ++mi)
            #pragma unroll
            for (int ni = 0; ni < 4; ++ni)
                acc[mi][ni] = __builtin_amdgcn_mfma_f32_16x16x32_bf16(af[mi], bfr[ni], acc[mi][ni], 0, 0, 0);
        __builtin_amdgcn_s_setprio(0);

        if (t + 2 < nt)
            asm volatile("s_waitcnt vmcnt(4)\n\ts_barrier" ::: "memory");  // tile t+1 ready; t+2 in flight
        else
            asm volatile("s_waitcnt vmcnt(0)\n\ts_barrier" ::: "memory");  // tail drain
        cur = (cur == 2) ? 0 : cur + 1;
    }

    #pragma unroll
    for (int mi = 0; mi < 4; ++mi) {
        int rowb = row0 + wm + mi * 16 + fg * 4;
        #pragma unroll
        for (int ni = 0; ni < 4; ++ni) {
            int col = col0 + wn + ni * 16 + fr;
            float bv = bias[col];
            #pragma unroll
            for (int r = 0; r < 4; ++r) {
                float v = acc[mi][ni][r] + bv;
                int rr = rowb + r;
                if (EPI == 0) {
                    int part = col >> 10, c = col & 1023;
                    int h = c >> 6, d = c & 63;
                    int b = rr >> 11, t = rr & 2047;
                    if (part == 0) v *= 0.18033688011112042f;   // fold log2(e)/sqrt(D) into Q
                    size_t idx;
                    if (part == 2)
                        idx = (size_t)2 * BHTD_ + ((size_t)(b * H_ + h) * D_ + d) * T_ + t;
                    else
                        idx = (size_t)part * BHTD_ + ((size_t)(b * H_ + h) * T_ + t) * D_ + d;
                    out_bf16[idx] = f32_bf16(v);
                } else {
                    out_f32[(size_t)rr * N + col] = v;
                }
            }
        }
    }
}

// ---------------- causal flash attention (v8 structure + T5 setprio) ----------------
// 512 blocks x 256 threads; dual-stream balanced blocks (chlo=i, chhi=31-i);
// every block = 33 stream-tile units; swapped-operand QK/PV; no-max softmax;
// K/V^T dbuf in swizzled LDS; reg prefetch of t+1 before compute of t.
__global__ __launch_bounds__(256) void attn_kernel(
    const unsigned short* __restrict__ qg,
    const unsigned short* __restrict__ kg,
    const unsigned short* __restrict__ vtg,  // [bh][D][T]
    unsigned short* __restrict__ y)
{
    const int id = blockIdx.x;
    const int xcd = id & 7, loc = id >> 3;
    const int bh = xcd * 4 + (loc & 3);      // 4 heads per XCD -> K/V L2-resident
    const int iq = loc >> 2;                 // [0,16)
    const int chlo = iq, chhi = 31 - iq;     // 64-row q chunks
    const int b = bh >> 4, h = bh & 15;
    const int tid = threadIdx.x, wid = tid >> 6, lane = tid & 63;
    const int fr = lane & 15, fg = lane >> 4;

    const unsigned short* qp = qg + (size_t)bh * (T_ * D_);
    const unsigned short* kp = kg + (size_t)bh * (T_ * D_);
    const unsigned short* vp = vtg + (size_t)bh * (D_ * T_);

    __shared__ __align__(16) char Ks[2][64 * 128];   // [kv][d] bf16, swizzled
    __shared__ __align__(16) char Vs[2][64 * 128];   // [d][kv] bf16, swizzled
    __shared__ __align__(16) char Ps[4][32 * 128];   // per-wave P: [stream*16+row][kv]
    char* Pw = Ps[wid];

    const int rhi = chhi * 64 + wid * 16;
    const int rlo = chlo * 64 + wid * 16;

    const int srow = tid >> 3;
    const int scb  = (tid & 7) * 16;
    const int sws  = scb ^ ((srow & 7) << 4);

    bf16x8 qhi[2], qlo[2];
    #pragma unroll
    for (int kd = 0; kd < 2; ++kd) {
        qhi[kd] = *(const bf16x8*)(qp + (size_t)(rhi + fr) * D_ + kd * 32 + fg * 8);
        qlo[kd] = *(const bf16x8*)(qp + (size_t)(rlo + fr) * D_ + kd * 32 + fg * 8);
    }

    f32x4 oHi[4], oLo[4];
    float lHi = 0.f, lLo = 0.f;
    #pragma unroll
    for (int n = 0; n < 4; ++n) {
        oHi[n] = (f32x4){0.f, 0.f, 0.f, 0.f};
        oLo[n] = (f32x4){0.f, 0.f, 0.f, 0.f};
    }

    const int ntk  = chhi + 1;
    const int ntlo = chlo + 1;

    // prologue: stage tile 0 into buffer 0
    {
        uint4 k0 = *(const uint4*)(kp + (size_t)srow        * D_ + (scb >> 1));
        uint4 k1 = *(const uint4*)(kp + (size_t)(srow + 32) * D_ + (scb >> 1));
        uint4 v0 = *(const uint4*)(vp + (size_t)srow        * T_ + (scb >> 1));
        uint4 v1 = *(const uint4*)(vp + (size_t)(srow + 32) * T_ + (scb >> 1));
        *(uint4*)(Ks[0] + srow * 128 + sws)        = k0;
        *(uint4*)(Ks[0] + (srow + 32) * 128 + sws) = k1;
        *(uint4*)(Vs[0] + srow * 128 + sws)        = v0;
        *(uint4*)(Vs[0] + (srow + 32) * 128 + sws) = v1;
    }
    __syncthreads();

    int cur = 0;
    for (int t = 0; t < ntk; ++t) {
        const int kv0 = t * 64;
        const int kv1 = (t + 1 < ntk) ? kv0 + 64 : kv0;

        // prefetch tile t+1 global->reg (lands under this tile's compute)
        uint4 pk0 = *(const uint4*)(kp + (size_t)(kv1 + srow)      * D_ + (scb >> 1));
        uint4 pk1 = *(const uint4*)(kp + (size_t)(kv1 + srow + 32) * D_ + (scb >> 1));
        uint4 pv0 = *(const uint4*)(vp + (size_t)srow        * T_ + kv1 + (scb >> 1));
        uint4 pv1 = *(const uint4*)(vp + (size_t)(srow + 32) * T_ + kv1 + (scb >> 1));

        const char* Kb = Ks[cur];
        const char* Vb = Vs[cur];
        const unsigned lsw = (unsigned)((fr & 7) << 4);
        const bool lo_act = (t < ntlo);      // block-uniform

        // ---- S^T = mfma(K, Q), both streams ----
        f32x4 sh[4], sl[4];
        #pragma unroll
        for (int n = 0; n < 4; ++n) {
            sh[n] = (f32x4){0.f, 0.f, 0.f, 0.f};
            sl[n] = (f32x4){0.f, 0.f, 0.f, 0.f};
        }
        __builtin_amdgcn_s_setprio(1);
        #pragma unroll
        for (int kd = 0; kd < 2; ++kd)
            #pragma unroll
            for (int n = 0; n < 4; ++n) {
                bf16x8 kf = *(const bf16x8*)(Kb + (n * 16 + fr) * 128 +
                                             (((unsigned)(kd * 64 + fg * 16)) ^ lsw));
                sh[n] = __builtin_amdgcn_mfma_f32_16x16x32_bf16(kf, qhi[kd], sh[n], 0, 0, 0);
                if (lo_act)
                    sl[n] = __builtin_amdgcn_mfma_f32_16x16x32_bf16(kf, qlo[kd], sl[n], 0, 0, 0);
            }
        __builtin_amdgcn_s_setprio(0);

        // ---- V^T frags hoisted (shared by both streams) ----
        bf16x8 vf[4][2];
        #pragma unroll
        for (int nd = 0; nd < 4; ++nd)
            #pragma unroll
            for (int kk = 0; kk < 2; ++kk)
                vf[nd][kk] = *(const bf16x8*)(Vb + (nd * 16 + fr) * 128 +
                                              (((unsigned)(kk * 64 + fg * 16)) ^ lsw));

        // ---- hi: softmax + P write ----
        {
            const bool masked = (t == chhi);
            const int qrow = rhi + fr;
            const unsigned prow = (unsigned)fr * 128;
            #pragma unroll
            for (int n = 0; n < 4; ++n) {
                float x0 = sh[n][0], x1 = sh[n][1], x2 = sh[n][2], x3 = sh[n][3];
                if (masked) {
                    const int kvb = kv0 + n * 16 + fg * 4;
                    if (kvb     > qrow) x0 = -1e30f;
                    if (kvb + 1 > qrow) x1 = -1e30f;
                    if (kvb + 2 > qrow) x2 = -1e30f;
                    if (kvb + 3 > qrow) x3 = -1e30f;
                }
                const float p0 = exp2f(x0), p1 = exp2f(x1);
                const float p2 = exp2f(x2), p3 = exp2f(x3);
                lHi += (p0 + p1) + (p2 + p3);
                bf16x4 pk4 = {(__bf16)p0, (__bf16)p1, (__bf16)p2, (__bf16)p3};
                *(uint2*)(Pw + ((prow + (unsigned)(n * 32 + fg * 8)) ^ lsw)) =
                    __builtin_bit_cast(uint2, pk4);
            }
        }
        // ---- hi: PV ----
        {
            const unsigned prow = (unsigned)fr * 128;
            __builtin_amdgcn_s_setprio(1);
            #pragma unroll
            for (int kk = 0; kk < 2; ++kk) {
                bf16x8 pb = *(const bf16x8*)(Pw + ((prow + (unsigned)(kk * 64 + fg * 16)) ^ lsw));
                #pragma unroll
                for (int nd = 0; nd < 4; ++nd)
                    oHi[nd] = __builtin_amdgcn_mfma_f32_16x16x32_bf16(vf[nd][kk], pb, oHi[nd], 0, 0, 0);
            }
            __builtin_amdgcn_s_setprio(0);
        }
        // ---- lo: softmax + P write + PV ----
        if (lo_act) {
            const bool masked = (t == chlo);
            const int qrow = rlo + fr;
            const unsigned prow = (unsigned)(16 + fr) * 128;
            #pragma unroll
            for (int n = 0; n < 4; ++n) {
                float x0 = sl[n][0], x1 = sl[n][1], x2 = sl[n][2], x3 = sl[n][3];
                if (masked) {
                    const int kvb = kv0 + n * 16 + fg * 4;
                    if (kvb     > qrow) x0 = -1e30f;
                    if (kvb + 1 > qrow) x1 = -1e30f;
                    if (kvb + 2 > qrow) x2 = -1e30f;
                    if (kvb + 3 > qrow) x3 = -1e30f;
                }
                const float p0 = exp2f(x0), p1 = exp2f(x1);
                const float p2 = exp2f(x2), p3 = exp2f(x3);
                lLo += (p0 + p1) + (p2 + p3);
                bf16x4 pk4 = {(__bf16)p0, (__bf16)p1, (__bf16)p2, (__bf16)p3};
                *(uint2*)(Pw + ((prow + (unsigned)(n * 32 + fg * 8)) ^ lsw)) =
                    __builtin_bit_cast(uint2, pk4);
            }
            const unsigned prow2 = (unsigned)(16 + fr) * 128;
            __builtin_amdgcn_s_setprio(1);
            #pragma unroll
            for (int kk = 0; kk < 2; ++kk) {
                bf16x8 pb = *(const bf16x8*)(Pw + ((prow2 + (unsigned)(kk * 64 + fg * 16)) ^ lsw));
                #pragma unroll
                for (int nd = 0; nd < 4; ++nd)
                    oLo[nd] = __builtin_amdgcn_mfma_f32_16x16x32_bf16(vf[nd][kk], pb, oLo[nd], 0, 0, 0);
            }
            __builtin_amdgcn_s_setprio(0);
        }

        // write prefetched tile into the other buffer, then barrier
        {
            char* Kn = Ks[cur ^ 1];
            char* Vn = Vs[cur ^ 1];
            *(uint4*)(Kn + srow * 128 + sws)        = pk0;
            *(uint4*)(Kn + (srow + 32) * 128 + sws) = pk1;
            *(uint4*)(Vn + srow * 128 + sws)        = pv0;
            *(uint4*)(Vn + (srow + 32) * 128 + sws) = pv1;
        }
        __syncthreads();
        cur ^= 1;
    }

    // ---- epilogue: reduce l over fg groups, normalize, packed stores ----
    #pragma unroll
    for (int s = 0; s < 2; ++s) {
        float rs = s ? lLo : lHi;
        rs += __shfl_xor(rs, 16);
        rs += __shfl_xor(rs, 32);
        const float inv = 1.f / rs;
        const int trow = (s ? rlo : rhi) + fr;
        f32x4* oT = s ? oLo : oHi;
        #pragma unroll
        for (int nd = 0; nd < 4; ++nd) {
            bf16x4 ov = {(__bf16)(oT[nd][0] * inv), (__bf16)(oT[nd][1] * inv),
                         (__bf16)(oT[nd][2] * inv), (__bf16)(oT[nd][3] * inv)};
            *(uint2*)(y + ((size_t)b * T_ + trow) * C_ + h * 64 + nd * 16 + fg * 4) =
                __builtin_bit_cast(uint2, ov);
        }
    }
}

// ---------------- launch ----------------
extern "C" void kernel_launch(void* const* d_in, const int* in_sizes, int n_in,
                              void* d_out, int out_size, void* d_ws, size_t ws_size,
                              hipStream_t stream) {
    const float* x     = (const float*)d_in[0];
    const float* Wqkv  = (const float*)d_in[1];
    const float* bqkv  = (const float*)d_in[2];
    const float* Wproj = (const float*)d_in[3];
    const float* bproj = (const float*)d_in[4];
    float* out = (float*)d_out;

    char* ws = (char*)d_ws;
    unsigned short* x_bf    = (unsigned short*)(ws);                 //  8 MB
    unsigned short* wqkv_t  = (unsigned short*)(ws + 8388608);       //  6 MB
    unsigned short* wproj_t = (unsigned short*)(ws + 14680064);      //  2 MB
    unsigned short* qkv     = (unsigned short*)(ws + 16777216);      // 24 MB
    unsigned short* ybuf    = (unsigned short*)(ws + 41943040);      //  8 MB

    cast_kernel<<<(M_ * C_) / 4 / 256, 256, 0, stream>>>(x, x_bf, M_ * C_);
    transpose_cast_kernel<<<dim3(3072 / 32, 1024 / 32), dim3(32, 8), 0, stream>>>(Wqkv, wqkv_t, 1024, 3072);
    transpose_cast_kernel<<<dim3(1024 / 32, 1024 / 32), dim3(32, 8), 0, stream>>>(Wproj, wproj_t, 1024, 1024);

    gemm_bt<0><<<dim3(M_ / 128, 3072 / 128), 256, 0, stream>>>(
        x_bf, wqkv_t, bqkv, qkv, nullptr, M_, 3072, 1024);

    attn_kernel<<<dim3(512), 256, 0, stream>>>(
        qkv, qkv + (size_t)BHTD_, qkv + 2 * (size_t)BHTD_, ybuf);

    gemm_bt<1><<<dim3(M_ / 128, 1024 / 128), 256, 0, stream>>>(
        ybuf, wproj_t, bproj, nullptr, out, M_, 1024, 1024);
}

// Round 12
// 123.441 us; speedup vs baseline: 1.0936x; 1.0352x over previous
//
#include <hip/hip_runtime.h>
#include <stdint.h>

#define B_ 2
#define T_ 2048
#define C_ 1024
#define H_ 16
#define D_ 64
#define M_ (B_*T_)
#define BHTD_ (B_*H_*T_*D_)

typedef __bf16 bf16x8 __attribute__((ext_vector_type(8)));
typedef __bf16 bf16x4 __attribute__((ext_vector_type(4)));
typedef float f32x4 __attribute__((ext_vector_type(4)));

static __device__ __forceinline__ unsigned short f32_bf16(float f) {
    unsigned int u = __float_as_uint(f);
    u += 0x7FFFu + ((u >> 16) & 1u);   // round-to-nearest-even
    return (unsigned short)(u >> 16);
}

// ---------------- fused prep: cast x + transpose both W (one launch) ----------------
// blocks [0,4096): cast x f32->bf16; [4096,7168): Wqkv [1024][3072] -> [3072][1024];
// [7168,8192): Wproj [1024][1024] -> [1024][1024] transposed. 256 threads each.
__global__ void prep_kernel(const float* __restrict__ x, unsigned short* __restrict__ xbf,
                            const float* __restrict__ Wqkv, unsigned short* __restrict__ wqkv_t,
                            const float* __restrict__ Wproj, unsigned short* __restrict__ wproj_t) {
    __shared__ float tile[32][33];
    const int id = blockIdx.x;
    const int tid = threadIdx.x;
    if (id < 4096) {
        int i = (id * 256 + tid) * 4;
        float4 f = *(const float4*)(x + i);
        ushort4 o;
        o.x = f32_bf16(f.x); o.y = f32_bf16(f.y); o.z = f32_bf16(f.z); o.w = f32_bf16(f.w);
        *(ushort4*)(xbf + i) = o;
        return;
    }
    const float* W; unsigned short* Wt; int K, N, bx, by;
    if (id < 7168) {
        int r = id - 4096; W = Wqkv; Wt = wqkv_t; K = 1024; N = 3072;
        bx = r % 96; by = r / 96;
    } else {
        int r = id - 7168; W = Wproj; Wt = wproj_t; K = 1024; N = 1024;
        bx = r & 31; by = r >> 5;
    }
    int n0 = bx * 32, k0 = by * 32;
    int tx = tid & 31, ty = tid >> 5;
    #pragma unroll
    for (int j = 0; j < 32; j += 8)
        tile[ty + j][tx] = W[(size_t)(k0 + ty + j) * N + n0 + tx];
    __syncthreads();
    #pragma unroll
    for (int j = 0; j < 32; j += 8)
        Wt[(size_t)(n0 + ty + j) * K + k0 + tx] = f32_bf16(tile[tx][ty + j]);
}

// ---------------- GEMM: 2-phase dbuf gll staging (round-8 proven K-loop) ----------------
// EPI=0 V-blocks (col0>=2048): epilogue transposes tile through LDS so the
// [bh][D][T] stores are 128B-contiguous (was: 2B scattered at 4KB stride).
template<int EPI>
__global__ __launch_bounds__(256) void gemm_bt(
    const unsigned short* __restrict__ A,
    const unsigned short* __restrict__ Bt,
    const float* __restrict__ bias,
    unsigned short* __restrict__ out_bf16,
    float* __restrict__ out_f32,
    int M, int N, int K)
{
    // union: staging (2x4096 + 2x4096 ushort = 32KB) | transpose buf 128x130 ushort
    __shared__ __align__(16) unsigned short smem[16640];
    unsigned short* AsU = smem;            // [2][4096]
    unsigned short* BsU = smem + 8192;     // [2][4096]
    int tid = threadIdx.x;
    int lane = tid & 63, wid = tid >> 6;
    int fr = lane & 15, fg = lane >> 4;
    int row0 = blockIdx.x * 128, col0 = blockIdx.y * 128;
    int wm = (wid >> 1) * 64, wn = (wid & 1) * 64;

    f32x4 acc[4][4];
    #pragma unroll
    for (int i = 0; i < 4; ++i)
        #pragma unroll
        for (int j = 0; j < 4; ++j)
            acc[i][j] = (f32x4){0.f, 0.f, 0.f, 0.f};

    const int srw = lane >> 2;
    const int scl = (lane & 3) * 8;
    const int c0 = wid * 2, c1 = wid * 2 + 1;

    auto stage = [&](int buf, int k0) {
        __builtin_amdgcn_global_load_lds(
            (const __attribute__((address_space(1))) void*)(A + (size_t)(row0 + c0 * 16 + srw) * K + k0 + scl),
            (__attribute__((address_space(3))) void*)(AsU + buf * 4096 + c0 * 512), 16, 0, 0);
        __builtin_amdgcn_global_load_lds(
            (const __attribute__((address_space(1))) void*)(A + (size_t)(row0 + c1 * 16 + srw) * K + k0 + scl),
            (__attribute__((address_space(3))) void*)(AsU + buf * 4096 + c1 * 512), 16, 0, 0);
        __builtin_amdgcn_global_load_lds(
            (const __attribute__((address_space(1))) void*)(Bt + (size_t)(col0 + c0 * 16 + srw) * K + k0 + scl),
            (__attribute__((address_space(3))) void*)(BsU + buf * 4096 + c0 * 512), 16, 0, 0);
        __builtin_amdgcn_global_load_lds(
            (const __attribute__((address_space(1))) void*)(Bt + (size_t)(col0 + c1 * 16 + srw) * K + k0 + scl),
            (__attribute__((address_space(3))) void*)(BsU + buf * 4096 + c1 * 512), 16, 0, 0);
    };

    stage(0, 0);
    __syncthreads();

    int cur = 0;
    for (int k0 = 0; k0 < K; k0 += 32) {
        if (k0 + 32 < K) stage(cur ^ 1, k0 + 32);

        bf16x8 af[4], bfr[4];
        #pragma unroll
        for (int i = 0; i < 4; ++i) {
            af[i]  = *(const bf16x8*)(AsU + cur * 4096 + (wm + i * 16 + fr) * 32 + fg * 8);
            bfr[i] = *(const bf16x8*)(BsU + cur * 4096 + (wn + i * 16 + fr) * 32 + fg * 8);
        }
        #pragma unroll
        for (int mi = 0; mi < 4; ++mi)
            #pragma unroll
            for (int ni = 0; ni < 4; ++ni)
                acc[mi][ni] = __builtin_amdgcn_mfma_f32_16x16x32_bf16(af[mi], bfr[ni], acc[mi][ni], 0, 0, 0);

        __syncthreads();
        cur ^= 1;
    }

    if (EPI == 0 && col0 >= 2048) {
        // ---- V blocks: transpose through LDS, coalesced [d][T] stores ----
        // write acc -> smem[col_local][row_local], stride 130 (65 dwords, coprime 32)
        #pragma unroll
        for (int ni = 0; ni < 4; ++ni) {
            const int cl = wn + ni * 16 + fr;
            const float bv = bias[col0 + cl];
            #pragma unroll
            for (int mi = 0; mi < 4; ++mi) {
                const int rl = wm + mi * 16 + fg * 4;
                bf16x4 pk = {(__bf16)(acc[mi][ni][0] + bv), (__bf16)(acc[mi][ni][1] + bv),
                             (__bf16)(acc[mi][ni][2] + bv), (__bf16)(acc[mi][ni][3] + bv)};
                uint2 w = __builtin_bit_cast(uint2, pk);
                *(unsigned int*)(smem + cl * 130 + rl)     = w.x;
                *(unsigned int*)(smem + cl * 130 + rl + 2) = w.y;
            }
        }
        __syncthreads();
        // read back: thread -> (col c, half): 64 t-values = 128B contiguous store
        const int c = tid >> 1, half = tid & 1;
        const int col = col0 + c;
        const int d = col & 63, h2 = (col >> 6) & 15;
        const int bb = row0 >> 11;
        const int t0 = (row0 & 2047) + half * 64;
        unsigned short* dst = out_bf16 + (size_t)2 * BHTD_ +
                              ((size_t)(bb * H_ + h2) * D_ + d) * T_ + t0;
        const unsigned short* src = smem + c * 130 + half * 64;
        #pragma unroll
        for (int j = 0; j < 8; ++j) {
            uint4 v;
            v.x = *(const unsigned int*)(src + j * 8 + 0);
            v.y = *(const unsigned int*)(src + j * 8 + 2);
            v.z = *(const unsigned int*)(src + j * 8 + 4);
            v.w = *(const unsigned int*)(src + j * 8 + 6);
            *(uint4*)(dst + j * 8) = v;
        }
        return;
    }

    #pragma unroll
    for (int mi = 0; mi < 4; ++mi) {
        int rowb = row0 + wm + mi * 16 + fg * 4;
        #pragma unroll
        for (int ni = 0; ni < 4; ++ni) {
            int col = col0 + wn + ni * 16 + fr;
            float bv = bias[col];
            #pragma unroll
            for (int r = 0; r < 4; ++r) {
                float v = acc[mi][ni][r] + bv;
                int rr = rowb + r;
                if (EPI == 0) {
                    int part = col >> 10, c = col & 1023;
                    int h = c >> 6, d = c & 63;
                    int b = rr >> 11, t = rr & 2047;
                    if (part == 0) v *= 0.18033688011112042f;   // fold log2(e)/sqrt(D) into Q
                    size_t idx = (size_t)part * BHTD_ + ((size_t)(b * H_ + h) * T_ + t) * D_ + d;
                    out_bf16[idx] = f32_bf16(v);
                } else {
                    out_f32[(size_t)rr * N + col] = v;
                }
            }
        }
    }
}

// ---------------- causal flash attention (v8 structure + setprio, unchanged) ----------------
__global__ __launch_bounds__(256) void attn_kernel(
    const unsigned short* __restrict__ qg,
    const unsigned short* __restrict__ kg,
    const unsigned short* __restrict__ vtg,  // [bh][D][T]
    unsigned short* __restrict__ y)
{
    const int id = blockIdx.x;
    const int xcd = id & 7, loc = id >> 3;
    const int bh = xcd * 4 + (loc & 3);      // 4 heads per XCD -> K/V L2-resident
    const int iq = loc >> 2;                 // [0,16)
    const int chlo = iq, chhi = 31 - iq;     // 64-row q chunks
    const int b = bh >> 4, h = bh & 15;
    const int tid = threadIdx.x, wid = tid >> 6, lane = tid & 63;
    const int fr = lane & 15, fg = lane >> 4;

    const unsigned short* qp = qg + (size_t)bh * (T_ * D_);
    const unsigned short* kp = kg + (size_t)bh * (T_ * D_);
    const unsigned short* vp = vtg + (size_t)bh * (D_ * T_);

    __shared__ __align__(16) char Ks[2][64 * 128];   // [kv][d] bf16, swizzled
    __shared__ __align__(16) char Vs[2][64 * 128];   // [d][kv] bf16, swizzled
    __shared__ __align__(16) char Ps[4][32 * 128];   // per-wave P: [stream*16+row][kv]
    char* Pw = Ps[wid];

    const int rhi = chhi * 64 + wid * 16;
    const int rlo = chlo * 64 + wid * 16;

    const int srow = tid >> 3;
    const int scb  = (tid & 7) * 16;
    const int sws  = scb ^ ((srow & 7) << 4);

    bf16x8 qhi[2], qlo[2];
    #pragma unroll
    for (int kd = 0; kd < 2; ++kd) {
        qhi[kd] = *(const bf16x8*)(qp + (size_t)(rhi + fr) * D_ + kd * 32 + fg * 8);
        qlo[kd] = *(const bf16x8*)(qp + (size_t)(rlo + fr) * D_ + kd * 32 + fg * 8);
    }

    f32x4 oHi[4], oLo[4];
    float lHi = 0.f, lLo = 0.f;
    #pragma unroll
    for (int n = 0; n < 4; ++n) {
        oHi[n] = (f32x4){0.f, 0.f, 0.f, 0.f};
        oLo[n] = (f32x4){0.f, 0.f, 0.f, 0.f};
    }

    const int ntk  = chhi + 1;
    const int ntlo = chlo + 1;

    {
        uint4 k0 = *(const uint4*)(kp + (size_t)srow        * D_ + (scb >> 1));
        uint4 k1 = *(const uint4*)(kp + (size_t)(srow + 32) * D_ + (scb >> 1));
        uint4 v0 = *(const uint4*)(vp + (size_t)srow        * T_ + (scb >> 1));
        uint4 v1 = *(const uint4*)(vp + (size_t)(srow + 32) * T_ + (scb >> 1));
        *(uint4*)(Ks[0] + srow * 128 + sws)        = k0;
        *(uint4*)(Ks[0] + (srow + 32) * 128 + sws) = k1;
        *(uint4*)(Vs[0] + srow * 128 + sws)        = v0;
        *(uint4*)(Vs[0] + (srow + 32) * 128 + sws) = v1;
    }
    __syncthreads();

    int cur = 0;
    for (int t = 0; t < ntk; ++t) {
        const int kv0 = t * 64;
        const int kv1 = (t + 1 < ntk) ? kv0 + 64 : kv0;

        uint4 pk0 = *(const uint4*)(kp + (size_t)(kv1 + srow)      * D_ + (scb >> 1));
        uint4 pk1 = *(const uint4*)(kp + (size_t)(kv1 + srow + 32) * D_ + (scb >> 1));
        uint4 pv0 = *(const uint4*)(vp + (size_t)srow        * T_ + kv1 + (scb >> 1));
        uint4 pv1 = *(const uint4*)(vp + (size_t)(srow + 32) * T_ + kv1 + (scb >> 1));

        const char* Kb = Ks[cur];
        const char* Vb = Vs[cur];
        const unsigned lsw = (unsigned)((fr & 7) << 4);
        const bool lo_act = (t < ntlo);

        f32x4 sh[4], sl[4];
        #pragma unroll
        for (int n = 0; n < 4; ++n) {
            sh[n] = (f32x4){0.f, 0.f, 0.f, 0.f};
            sl[n] = (f32x4){0.f, 0.f, 0.f, 0.f};
        }
        __builtin_amdgcn_s_setprio(1);
        #pragma unroll
        for (int kd = 0; kd < 2; ++kd)
            #pragma unroll
            for (int n = 0; n < 4; ++n) {
                bf16x8 kf = *(const bf16x8*)(Kb + (n * 16 + fr) * 128 +
                                             (((unsigned)(kd * 64 + fg * 16)) ^ lsw));
                sh[n] = __builtin_amdgcn_mfma_f32_16x16x32_bf16(kf, qhi[kd], sh[n], 0, 0, 0);
                if (lo_act)
                    sl[n] = __builtin_amdgcn_mfma_f32_16x16x32_bf16(kf, qlo[kd], sl[n], 0, 0, 0);
            }
        __builtin_amdgcn_s_setprio(0);

        bf16x8 vf[4][2];
        #pragma unroll
        for (int nd = 0; nd < 4; ++nd)
            #pragma unroll
            for (int kk = 0; kk < 2; ++kk)
                vf[nd][kk] = *(const bf16x8*)(Vb + (nd * 16 + fr) * 128 +
                                              (((unsigned)(kk * 64 + fg * 16)) ^ lsw));

        {
            const bool masked = (t == chhi);
            const int qrow = rhi + fr;
            const unsigned prow = (unsigned)fr * 128;
            #pragma unroll
            for (int n = 0; n < 4; ++n) {
                float x0 = sh[n][0], x1 = sh[n][1], x2 = sh[n][2], x3 = sh[n][3];
                if (masked) {
                    const int kvb = kv0 + n * 16 + fg * 4;
                    if (kvb     > qrow) x0 = -1e30f;
                    if (kvb + 1 > qrow) x1 = -1e30f;
                    if (kvb + 2 > qrow) x2 = -1e30f;
                    if (kvb + 3 > qrow) x3 = -1e30f;
                }
                const float p0 = exp2f(x0), p1 = exp2f(x1);
                const float p2 = exp2f(x2), p3 = exp2f(x3);
                lHi += (p0 + p1) + (p2 + p3);
                bf16x4 pk4 = {(__bf16)p0, (__bf16)p1, (__bf16)p2, (__bf16)p3};
                *(uint2*)(Pw + ((prow + (unsigned)(n * 32 + fg * 8)) ^ lsw)) =
                    __builtin_bit_cast(uint2, pk4);
            }
        }
        {
            const unsigned prow = (unsigned)fr * 128;
            __builtin_amdgcn_s_setprio(1);
            #pragma unroll
            for (int kk = 0; kk < 2; ++kk) {
                bf16x8 pb = *(const bf16x8*)(Pw + ((prow + (unsigned)(kk * 64 + fg * 16)) ^ lsw));
                #pragma unroll
                for (int nd = 0; nd < 4; ++nd)
                    oHi[nd] = __builtin_amdgcn_mfma_f32_16x16x32_bf16(vf[nd][kk], pb, oHi[nd], 0, 0, 0);
            }
            __builtin_amdgcn_s_setprio(0);
        }
        if (lo_act) {
            const bool masked = (t == chlo);
            const int qrow = rlo + fr;
            const unsigned prow = (unsigned)(16 + fr) * 128;
            #pragma unroll
            for (int n = 0; n < 4; ++n) {
                float x0 = sl[n][0], x1 = sl[n][1], x2 = sl[n][2], x3 = sl[n][3];
                if (masked) {
                    const int kvb = kv0 + n * 16 + fg * 4;
                    if (kvb     > qrow) x0 = -1e30f;
                    if (kvb + 1 > qrow) x1 = -1e30f;
                    if (kvb + 2 > qrow) x2 = -1e30f;
                    if (kvb + 3 > qrow) x3 = -1e30f;
                }
                const float p0 = exp2f(x0), p1 = exp2f(x1);
                const float p2 = exp2f(x2), p3 = exp2f(x3);
                lLo += (p0 + p1) + (p2 + p3);
                bf16x4 pk4 = {(__bf16)p0, (__bf16)p1, (__bf16)p2, (__bf16)p3};
                *(uint2*)(Pw + ((prow + (unsigned)(n * 32 + fg * 8)) ^ lsw)) =
                    __builtin_bit_cast(uint2, pk4);
            }
            const unsigned prow2 = (unsigned)(16 + fr) * 128;
            __builtin_amdgcn_s_setprio(1);
            #pragma unroll
            for (int kk = 0; kk < 2; ++kk) {
                bf16x8 pb = *(const bf16x8*)(Pw + ((prow2 + (unsigned)(kk * 64 + fg * 16)) ^ lsw));
                #pragma unroll
                for (int nd = 0; nd < 4; ++nd)
                    oLo[nd] = __builtin_amdgcn_mfma_f32_16x16x32_bf16(vf[nd][kk], pb, oLo[nd], 0, 0, 0);
            }
            __builtin_amdgcn_s_setprio(0);
        }

        {
            char* Kn = Ks[cur ^ 1];
            char* Vn = Vs[cur ^ 1];
            *(uint4*)(Kn + srow * 128 + sws)        = pk0;
            *(uint4*)(Kn + (srow + 32) * 128 + sws) = pk1;
            *(uint4*)(Vn + srow * 128 + sws)        = pv0;
            *(uint4*)(Vn + (srow + 32) * 128 + sws) = pv1;
        }
        __syncthreads();
        cur ^= 1;
    }

    #pragma unroll
    for (int s = 0; s < 2; ++s) {
        float rs = s ? lLo : lHi;
        rs += __shfl_xor(rs, 16);
        rs += __shfl_xor(rs, 32);
        const float inv = 1.f / rs;
        const int trow = (s ? rlo : rhi) + fr;
        f32x4* oT = s ? oLo : oHi;
        #pragma unroll
        for (int nd = 0; nd < 4; ++nd) {
            bf16x4 ov = {(__bf16)(oT[nd][0] * inv), (__bf16)(oT[nd][1] * inv),
                         (__bf16)(oT[nd][2] * inv), (__bf16)(oT[nd][3] * inv)};
            *(uint2*)(y + ((size_t)b * T_ + trow) * C_ + h * 64 + nd * 16 + fg * 4) =
                __builtin_bit_cast(uint2, ov);
        }
    }
}

// ---------------- launch ----------------
extern "C" void kernel_launch(void* const* d_in, const int* in_sizes, int n_in,
                              void* d_out, int out_size, void* d_ws, size_t ws_size,
                              hipStream_t stream) {
    const float* x     = (const float*)d_in[0];
    const float* Wqkv  = (const float*)d_in[1];
    const float* bqkv  = (const float*)d_in[2];
    const float* Wproj = (const float*)d_in[3];
    const float* bproj = (const float*)d_in[4];
    float* out = (float*)d_out;

    char* ws = (char*)d_ws;
    unsigned short* x_bf    = (unsigned short*)(ws);                 //  8 MB
    unsigned short* wqkv_t  = (unsigned short*)(ws + 8388608);       //  6 MB
    unsigned short* wproj_t = (unsigned short*)(ws + 14680064);      //  2 MB
    unsigned short* qkv     = (unsigned short*)(ws + 16777216);      // 24 MB
    unsigned short* ybuf    = (unsigned short*)(ws + 41943040);      //  8 MB

    prep_kernel<<<dim3(8192), 256, 0, stream>>>(x, x_bf, Wqkv, wqkv_t, Wproj, wproj_t);

    gemm_bt<0><<<dim3(M_ / 128, 3072 / 128), 256, 0, stream>>>(
        x_bf, wqkv_t, bqkv, qkv, nullptr, M_, 3072, 1024);

    attn_kernel<<<dim3(512), 256, 0, stream>>>(
        qkv, qkv + (size_t)BHTD_, qkv + 2 * (size_t)BHTD_, ybuf);

    gemm_bt<1><<<dim3(M_ / 128, 1024 / 128), 256, 0, stream>>>(
        ybuf, wproj_t, bproj, nullptr, out, M_, 1024, 1024);
}

// Round 13
// 119.465 us; speedup vs baseline: 1.1300x; 1.0333x over previous
//
#include <hip/hip_runtime.h>
#include <stdint.h>

#define B_ 2
#define T_ 2048
#define C_ 1024
#define H_ 16
#define D_ 64
#define M_ (B_*T_)
#define BHTD_ (B_*H_*T_*D_)

typedef __bf16 bf16x8 __attribute__((ext_vector_type(8)));
typedef __bf16 bf16x4 __attribute__((ext_vector_type(4)));
typedef float f32x4 __attribute__((ext_vector_type(4)));

static __device__ __forceinline__ unsigned short f32_bf16(float f) {
    unsigned int u = __float_as_uint(f);
    u += 0x7FFFu + ((u >> 16) & 1u);   // round-to-nearest-even
    return (unsigned short)(u >> 16);
}

// ---------------- fused prep: cast x + transpose both W (one launch) ----------------
__global__ void prep_kernel(const float* __restrict__ x, unsigned short* __restrict__ xbf,
                            const float* __restrict__ Wqkv, unsigned short* __restrict__ wqkv_t,
                            const float* __restrict__ Wproj, unsigned short* __restrict__ wproj_t) {
    __shared__ float tile[32][33];
    const int id = blockIdx.x;
    const int tid = threadIdx.x;
    if (id < 4096) {
        int i = (id * 256 + tid) * 4;
        float4 f = *(const float4*)(x + i);
        ushort4 o;
        o.x = f32_bf16(f.x); o.y = f32_bf16(f.y); o.z = f32_bf16(f.z); o.w = f32_bf16(f.w);
        *(ushort4*)(xbf + i) = o;
        return;
    }
    const float* W; unsigned short* Wt; int K, N, bx, by;
    if (id < 7168) {
        int r = id - 4096; W = Wqkv; Wt = wqkv_t; K = 1024; N = 3072;
        bx = r % 96; by = r / 96;
    } else {
        int r = id - 7168; W = Wproj; Wt = wproj_t; K = 1024; N = 1024;
        bx = r & 31; by = r >> 5;
    }
    int n0 = bx * 32, k0 = by * 32;
    int tx = tid & 31, ty = tid >> 5;
    #pragma unroll
    for (int j = 0; j < 32; j += 8)
        tile[ty + j][tx] = W[(size_t)(k0 + ty + j) * N + n0 + tx];
    __syncthreads();
    #pragma unroll
    for (int j = 0; j < 32; j += 8)
        Wt[(size_t)(n0 + ty + j) * K + k0 + tx] = f32_bf16(tile[tx][ty + j]);
}

// ---------------- GEMM: 2-phase dbuf gll staging; tile 128 x BN ----------------
// BN=128: 4 waves in 2x2 (64x64 each). BN=64: 4 waves in 2x2 (64x32 each),
// grid doubles -> 2 blocks/CU for gemm1 (was 1/CU: staging latency exposed).
// EPI=0 V-blocks (col0>=2048): transpose epilogue -> coalesced [d][T] stores.
template<int EPI, int BN>
__global__ __launch_bounds__(256) void gemm_bt(
    const unsigned short* __restrict__ A,
    const unsigned short* __restrict__ Bt,
    const float* __restrict__ bias,
    unsigned short* __restrict__ out_bf16,
    float* __restrict__ out_f32,
    int M, int N, int K)
{
    constexpr int NI = (BN == 128) ? 4 : 2;      // 16-col frags per wave
    constexpr int BSTR = BN * 32;                 // B buffer stride (elems)
    __shared__ __align__(16) unsigned short smem[16640];
    unsigned short* AsU = smem;                   // [2][4096]
    unsigned short* BsU = smem + 8192;            // [2][BSTR]
    int tid = threadIdx.x;
    int lane = tid & 63, wid = tid >> 6;
    int fr = lane & 15, fg = lane >> 4;
    int row0 = blockIdx.x * 128, col0 = blockIdx.y * BN;
    int wm = (wid >> 1) * 64, wn = (wid & 1) * (BN / 2);

    f32x4 acc[4][NI];
    #pragma unroll
    for (int i = 0; i < 4; ++i)
        #pragma unroll
        for (int j = 0; j < NI; ++j)
            acc[i][j] = (f32x4){0.f, 0.f, 0.f, 0.f};

    const int srw = lane >> 2;
    const int scl = (lane & 3) * 8;
    const int c0 = wid * 2, c1 = wid * 2 + 1;

    auto stage = [&](int buf, int k0) {
        __builtin_amdgcn_global_load_lds(
            (const __attribute__((address_space(1))) void*)(A + (size_t)(row0 + c0 * 16 + srw) * K + k0 + scl),
            (__attribute__((address_space(3))) void*)(AsU + buf * 4096 + c0 * 512), 16, 0, 0);
        __builtin_amdgcn_global_load_lds(
            (const __attribute__((address_space(1))) void*)(A + (size_t)(row0 + c1 * 16 + srw) * K + k0 + scl),
            (__attribute__((address_space(3))) void*)(AsU + buf * 4096 + c1 * 512), 16, 0, 0);
        if (BN == 128) {
            __builtin_amdgcn_global_load_lds(
                (const __attribute__((address_space(1))) void*)(Bt + (size_t)(col0 + c0 * 16 + srw) * K + k0 + scl),
                (__attribute__((address_space(3))) void*)(BsU + buf * BSTR + c0 * 512), 16, 0, 0);
            __builtin_amdgcn_global_load_lds(
                (const __attribute__((address_space(1))) void*)(Bt + (size_t)(col0 + c1 * 16 + srw) * K + k0 + scl),
                (__attribute__((address_space(3))) void*)(BsU + buf * BSTR + c1 * 512), 16, 0, 0);
        } else {
            __builtin_amdgcn_global_load_lds(
                (const __attribute__((address_space(1))) void*)(Bt + (size_t)(col0 + wid * 16 + srw) * K + k0 + scl),
                (__attribute__((address_space(3))) void*)(BsU + buf * BSTR + wid * 512), 16, 0, 0);
        }
    };

    stage(0, 0);
    __syncthreads();

    int cur = 0;
    for (int k0 = 0; k0 < K; k0 += 32) {
        if (k0 + 32 < K) stage(cur ^ 1, k0 + 32);

        bf16x8 af[4], bfr[NI];
        #pragma unroll
        for (int i = 0; i < 4; ++i)
            af[i] = *(const bf16x8*)(AsU + cur * 4096 + (wm + i * 16 + fr) * 32 + fg * 8);
        #pragma unroll
        for (int i = 0; i < NI; ++i)
            bfr[i] = *(const bf16x8*)(BsU + cur * BSTR + (wn + i * 16 + fr) * 32 + fg * 8);
        #pragma unroll
        for (int mi = 0; mi < 4; ++mi)
            #pragma unroll
            for (int ni = 0; ni < NI; ++ni)
                acc[mi][ni] = __builtin_amdgcn_mfma_f32_16x16x32_bf16(af[mi], bfr[ni], acc[mi][ni], 0, 0, 0);

        __syncthreads();
        cur ^= 1;
    }

    if (EPI == 0 && BN == 128 && col0 >= 2048) {
        // ---- V blocks: transpose through LDS, coalesced [d][T] stores ----
        #pragma unroll
        for (int ni = 0; ni < NI; ++ni) {
            const int cl = wn + ni * 16 + fr;
            const float bv = bias[col0 + cl];
            #pragma unroll
            for (int mi = 0; mi < 4; ++mi) {
                const int rl = wm + mi * 16 + fg * 4;
                bf16x4 pk = {(__bf16)(acc[mi][ni][0] + bv), (__bf16)(acc[mi][ni][1] + bv),
                             (__bf16)(acc[mi][ni][2] + bv), (__bf16)(acc[mi][ni][3] + bv)};
                uint2 w = __builtin_bit_cast(uint2, pk);
                *(unsigned int*)(smem + cl * 130 + rl)     = w.x;
                *(unsigned int*)(smem + cl * 130 + rl + 2) = w.y;
            }
        }
        __syncthreads();
        const int c = tid >> 1, half = tid & 1;
        const int col = col0 + c;
        const int d = col & 63, h2 = (col >> 6) & 15;
        const int bb = row0 >> 11;
        const int t0 = (row0 & 2047) + half * 64;
        unsigned short* dst = out_bf16 + (size_t)2 * BHTD_ +
                              ((size_t)(bb * H_ + h2) * D_ + d) * T_ + t0;
        const unsigned short* src = smem + c * 130 + half * 64;
        #pragma unroll
        for (int j = 0; j < 8; ++j) {
            uint4 v;
            v.x = *(const unsigned int*)(src + j * 8 + 0);
            v.y = *(const unsigned int*)(src + j * 8 + 2);
            v.z = *(const unsigned int*)(src + j * 8 + 4);
            v.w = *(const unsigned int*)(src + j * 8 + 6);
            *(uint4*)(dst + j * 8) = v;
        }
        return;
    }

    #pragma unroll
    for (int mi = 0; mi < 4; ++mi) {
        int rowb = row0 + wm + mi * 16 + fg * 4;
        #pragma unroll
        for (int ni = 0; ni < NI; ++ni) {
            int col = col0 + wn + ni * 16 + fr;
            float bv = bias[col];
            #pragma unroll
            for (int r = 0; r < 4; ++r) {
                float v = acc[mi][ni][r] + bv;
                int rr = rowb + r;
                if (EPI == 0) {
                    int part = col >> 10, c = col & 1023;
                    int h = c >> 6, d = c & 63;
                    int b = rr >> 11, t = rr & 2047;
                    if (part == 0) v *= 0.18033688011112042f;   // fold log2(e)/sqrt(D) into Q
                    size_t idx = (size_t)part * BHTD_ + ((size_t)(b * H_ + h) * T_ + t) * D_ + d;
                    out_bf16[idx] = f32_bf16(v);
                } else {
                    out_f32[(size_t)rr * N + col] = v;
                }
            }
        }
    }
}

// ---------------- causal flash attention (v8 + setprio + duration-pairing perm) ----------------
// Co-CU blocks are (id, id+256) -> iq0 pairs (i, i+8). Perm iq = iq0<8 ? iq0 : 23-iq0
// makes co-resident block DURATIONS (ntk = 32-iq) sum to a constant 49.
__global__ __launch_bounds__(256) void attn_kernel(
    const unsigned short* __restrict__ qg,
    const unsigned short* __restrict__ kg,
    const unsigned short* __restrict__ vtg,  // [bh][D][T]
    unsigned short* __restrict__ y)
{
    const int id = blockIdx.x;
    const int xcd = id & 7, loc = id >> 3;
    const int bh = xcd * 4 + (loc & 3);      // 4 heads per XCD -> K/V L2-resident
    const int iq0 = loc >> 2;                // [0,16)
    const int iq = (iq0 < 8) ? iq0 : 23 - iq0;   // complementary co-CU durations
    const int chlo = iq, chhi = 31 - iq;     // 64-row q chunks
    const int b = bh >> 4, h = bh & 15;
    const int tid = threadIdx.x, wid = tid >> 6, lane = tid & 63;
    const int fr = lane & 15, fg = lane >> 4;

    const unsigned short* qp = qg + (size_t)bh * (T_ * D_);
    const unsigned short* kp = kg + (size_t)bh * (T_ * D_);
    const unsigned short* vp = vtg + (size_t)bh * (D_ * T_);

    __shared__ __align__(16) char Ks[2][64 * 128];   // [kv][d] bf16, swizzled
    __shared__ __align__(16) char Vs[2][64 * 128];   // [d][kv] bf16, swizzled
    __shared__ __align__(16) char Ps[4][32 * 128];   // per-wave P: [stream*16+row][kv]
    char* Pw = Ps[wid];

    const int rhi = chhi * 64 + wid * 16;
    const int rlo = chlo * 64 + wid * 16;

    const int srow = tid >> 3;
    const int scb  = (tid & 7) * 16;
    const int sws  = scb ^ ((srow & 7) << 4);

    bf16x8 qhi[2], qlo[2];
    #pragma unroll
    for (int kd = 0; kd < 2; ++kd) {
        qhi[kd] = *(const bf16x8*)(qp + (size_t)(rhi + fr) * D_ + kd * 32 + fg * 8);
        qlo[kd] = *(const bf16x8*)(qp + (size_t)(rlo + fr) * D_ + kd * 32 + fg * 8);
    }

    f32x4 oHi[4], oLo[4];
    float lHi = 0.f, lLo = 0.f;
    #pragma unroll
    for (int n = 0; n < 4; ++n) {
        oHi[n] = (f32x4){0.f, 0.f, 0.f, 0.f};
        oLo[n] = (f32x4){0.f, 0.f, 0.f, 0.f};
    }

    const int ntk  = chhi + 1;
    const int ntlo = chlo + 1;

    {
        uint4 k0 = *(const uint4*)(kp + (size_t)srow        * D_ + (scb >> 1));
        uint4 k1 = *(const uint4*)(kp + (size_t)(srow + 32) * D_ + (scb >> 1));
        uint4 v0 = *(const uint4*)(vp + (size_t)srow        * T_ + (scb >> 1));
        uint4 v1 = *(const uint4*)(vp + (size_t)(srow + 32) * T_ + (scb >> 1));
        *(uint4*)(Ks[0] + srow * 128 + sws)        = k0;
        *(uint4*)(Ks[0] + (srow + 32) * 128 + sws) = k1;
        *(uint4*)(Vs[0] + srow * 128 + sws)        = v0;
        *(uint4*)(Vs[0] + (srow + 32) * 128 + sws) = v1;
    }
    __syncthreads();

    int cur = 0;
    for (int t = 0; t < ntk; ++t) {
        const int kv0 = t * 64;
        const int kv1 = (t + 1 < ntk) ? kv0 + 64 : kv0;

        uint4 pk0 = *(const uint4*)(kp + (size_t)(kv1 + srow)      * D_ + (scb >> 1));
        uint4 pk1 = *(const uint4*)(kp + (size_t)(kv1 + srow + 32) * D_ + (scb >> 1));
        uint4 pv0 = *(const uint4*)(vp + (size_t)srow        * T_ + kv1 + (scb >> 1));
        uint4 pv1 = *(const uint4*)(vp + (size_t)(srow + 32) * T_ + kv1 + (scb >> 1));

        const char* Kb = Ks[cur];
        const char* Vb = Vs[cur];
        const unsigned lsw = (unsigned)((fr & 7) << 4);
        const bool lo_act = (t < ntlo);

        f32x4 sh[4], sl[4];
        #pragma unroll
        for (int n = 0; n < 4; ++n) {
            sh[n] = (f32x4){0.f, 0.f, 0.f, 0.f};
            sl[n] = (f32x4){0.f, 0.f, 0.f, 0.f};
        }
        __builtin_amdgcn_s_setprio(1);
        #pragma unroll
        for (int kd = 0; kd < 2; ++kd)
            #pragma unroll
            for (int n = 0; n < 4; ++n) {
                bf16x8 kf = *(const bf16x8*)(Kb + (n * 16 + fr) * 128 +
                                             (((unsigned)(kd * 64 + fg * 16)) ^ lsw));
                sh[n] = __builtin_amdgcn_mfma_f32_16x16x32_bf16(kf, qhi[kd], sh[n], 0, 0, 0);
                if (lo_act)
                    sl[n] = __builtin_amdgcn_mfma_f32_16x16x32_bf16(kf, qlo[kd], sl[n], 0, 0, 0);
            }
        __builtin_amdgcn_s_setprio(0);

        bf16x8 vf[4][2];
        #pragma unroll
        for (int nd = 0; nd < 4; ++nd)
            #pragma unroll
            for (int kk = 0; kk < 2; ++kk)
                vf[nd][kk] = *(const bf16x8*)(Vb + (nd * 16 + fr) * 128 +
                                              (((unsigned)(kk * 64 + fg * 16)) ^ lsw));

        {
            const bool masked = (t == chhi);
            const int qrow = rhi + fr;
            const unsigned prow = (unsigned)fr * 128;
            #pragma unroll
            for (int n = 0; n < 4; ++n) {
                float x0 = sh[n][0], x1 = sh[n][1], x2 = sh[n][2], x3 = sh[n][3];
                if (masked) {
                    const int kvb = kv0 + n * 16 + fg * 4;
                    if (kvb     > qrow) x0 = -1e30f;
                    if (kvb + 1 > qrow) x1 = -1e30f;
                    if (kvb + 2 > qrow) x2 = -1e30f;
                    if (kvb + 3 > qrow) x3 = -1e30f;
                }
                const float p0 = exp2f(x0), p1 = exp2f(x1);
                const float p2 = exp2f(x2), p3 = exp2f(x3);
                lHi += (p0 + p1) + (p2 + p3);
                bf16x4 pk4 = {(__bf16)p0, (__bf16)p1, (__bf16)p2, (__bf16)p3};
                *(uint2*)(Pw + ((prow + (unsigned)(n * 32 + fg * 8)) ^ lsw)) =
                    __builtin_bit_cast(uint2, pk4);
            }
        }
        {
            const unsigned prow = (unsigned)fr * 128;
            __builtin_amdgcn_s_setprio(1);
            #pragma unroll
            for (int kk = 0; kk < 2; ++kk) {
                bf16x8 pb = *(const bf16x8*)(Pw + ((prow + (unsigned)(kk * 64 + fg * 16)) ^ lsw));
                #pragma unroll
                for (int nd = 0; nd < 4; ++nd)
                    oHi[nd] = __builtin_amdgcn_mfma_f32_16x16x32_bf16(vf[nd][kk], pb, oHi[nd], 0, 0, 0);
            }
            __builtin_amdgcn_s_setprio(0);
        }
        if (lo_act) {
            const bool masked = (t == chlo);
            const int qrow = rlo + fr;
            const unsigned prow = (unsigned)(16 + fr) * 128;
            #pragma unroll
            for (int n = 0; n < 4; ++n) {
                float x0 = sl[n][0], x1 = sl[n][1], x2 = sl[n][2], x3 = sl[n][3];
                if (masked) {
                    const int kvb = kv0 + n * 16 + fg * 4;
                    if (kvb     > qrow) x0 = -1e30f;
                    if (kvb + 1 > qrow) x1 = -1e30f;
                    if (kvb + 2 > qrow) x2 = -1e30f;
                    if (kvb + 3 > qrow) x3 = -1e30f;
                }
                const float p0 = exp2f(x0), p1 = exp2f(x1);
                const float p2 = exp2f(x2), p3 = exp2f(x3);
                lLo += (p0 + p1) + (p2 + p3);
                bf16x4 pk4 = {(__bf16)p0, (__bf16)p1, (__bf16)p2, (__bf16)p3};
                *(uint2*)(Pw + ((prow + (unsigned)(n * 32 + fg * 8)) ^ lsw)) =
                    __builtin_bit_cast(uint2, pk4);
            }
            const unsigned prow2 = (unsigned)(16 + fr) * 128;
            __builtin_amdgcn_s_setprio(1);
            #pragma unroll
            for (int kk = 0; kk < 2; ++kk) {
                bf16x8 pb = *(const bf16x8*)(Pw + ((prow2 + (unsigned)(kk * 64 + fg * 16)) ^ lsw));
                #pragma unroll
                for (int nd = 0; nd < 4; ++nd)
                    oLo[nd] = __builtin_amdgcn_mfma_f32_16x16x32_bf16(vf[nd][kk], pb, oLo[nd], 0, 0, 0);
            }
            __builtin_amdgcn_s_setprio(0);
        }

        {
            char* Kn = Ks[cur ^ 1];
            char* Vn = Vs[cur ^ 1];
            *(uint4*)(Kn + srow * 128 + sws)        = pk0;
            *(uint4*)(Kn + (srow + 32) * 128 + sws) = pk1;
            *(uint4*)(Vn + srow * 128 + sws)        = pv0;
            *(uint4*)(Vn + (srow + 32) * 128 + sws) = pv1;
        }
        __syncthreads();
        cur ^= 1;
    }

    #pragma unroll
    for (int s = 0; s < 2; ++s) {
        float rs = s ? lLo : lHi;
        rs += __shfl_xor(rs, 16);
        rs += __shfl_xor(rs, 32);
        const float inv = 1.f / rs;
        const int trow = (s ? rlo : rhi) + fr;
        f32x4* oT = s ? oLo : oHi;
        #pragma unroll
        for (int nd = 0; nd < 4; ++nd) {
            bf16x4 ov = {(__bf16)(oT[nd][0] * inv), (__bf16)(oT[nd][1] * inv),
                         (__bf16)(oT[nd][2] * inv), (__bf16)(oT[nd][3] * inv)};
            *(uint2*)(y + ((size_t)b * T_ + trow) * C_ + h * 64 + nd * 16 + fg * 4) =
                __builtin_bit_cast(uint2, ov);
        }
    }
}

// ---------------- launch ----------------
extern "C" void kernel_launch(void* const* d_in, const int* in_sizes, int n_in,
                              void* d_out, int out_size, void* d_ws, size_t ws_size,
                              hipStream_t stream) {
    const float* x     = (const float*)d_in[0];
    const float* Wqkv  = (const float*)d_in[1];
    const float* bqkv  = (const float*)d_in[2];
    const float* Wproj = (const float*)d_in[3];
    const float* bproj = (const float*)d_in[4];
    float* out = (float*)d_out;

    char* ws = (char*)d_ws;
    unsigned short* x_bf    = (unsigned short*)(ws);                 //  8 MB
    unsigned short* wqkv_t  = (unsigned short*)(ws + 8388608);       //  6 MB
    unsigned short* wproj_t = (unsigned short*)(ws + 14680064);      //  2 MB
    unsigned short* qkv     = (unsigned short*)(ws + 16777216);      // 24 MB
    unsigned short* ybuf    = (unsigned short*)(ws + 41943040);      //  8 MB

    prep_kernel<<<dim3(8192), 256, 0, stream>>>(x, x_bf, Wqkv, wqkv_t, Wproj, wproj_t);

    gemm_bt<0, 128><<<dim3(M_ / 128, 3072 / 128), 256, 0, stream>>>(
        x_bf, wqkv_t, bqkv, qkv, nullptr, M_, 3072, 1024);

    attn_kernel<<<dim3(512), 256, 0, stream>>>(
        qkv, qkv + (size_t)BHTD_, qkv + 2 * (size_t)BHTD_, ybuf);

    gemm_bt<1, 64><<<dim3(M_ / 128, 1024 / 64), 256, 0, stream>>>(
        ybuf, wproj_t, bproj, nullptr, out, M_, 1024, 1024);
}